// Round 12
// baseline (444.157 us; speedup 1.0000x reference)
//
#include <hip/hip_runtime.h>
#include <hip/hip_bf16.h>
#include <math.h>

// Problem constants
#define N_NODES 30
#define E_BASE  82
#define E_TOT   112         // 82 edges + 30 self loops
#define B_GRAPH 1024
#define HID     256
#define NTOT    (B_GRAPH * N_NODES)   // 30720
#define MAXIN   32
#define N_EH    41
#define M_MLP   (B_GRAPH * N_EH)      // 41984

#define META_SRC  0
#define META_DST  E_TOT
#define META_CNT  (2 * E_TOT)
#define META_LIST 256
#define META_INTS 1216

typedef __attribute__((ext_vector_type(8))) short bf16x8;
typedef __attribute__((ext_vector_type(4))) short bf16x4;
typedef __attribute__((ext_vector_type(4))) float f32x4;
#define AS3 __attribute__((address_space(3)))
#define AS1 __attribute__((address_space(1)))

__device__ __forceinline__ void gload_lds16(const void* g, void* l) {
  __builtin_amdgcn_global_load_lds((const AS1 void*)g, (AS3 void*)l, 16, 0, 0);
}

// Bit-reinterpret ONLY — callers must pass raw bf16 bit patterns (short lanes
// of bf16x4/8 vectors). Never pass __hip_bfloat16 (would value-convert via
// float->short — the R3 NaN bug).
__device__ __forceinline__ float b2f(short s) {
  union { unsigned u; float f; } x;
  x.u = ((unsigned)(unsigned short)s) << 16;
  return x.f;
}

// float -> bf16 bit pattern (same rounding as __float2bfloat16; raw short out)
__device__ __forceinline__ short f2bf_bits(float f) {
  union { __hip_bfloat16 h; short s; } u;
  u.h = __float2bfloat16(f);
  return u.s;
}

// ---------------------------------------------------------------------------
// Transpose-cast all weights fp32 [K,N] -> bf16 [N,K]. Block 976 builds the
// base-graph CSR (R21: slist entries PACKED as (e<<8)|src). Blocks 977+ zero
// the logit accumulators (replaces the hipMemsetAsync launch).
// ---------------------------------------------------------------------------
struct WtJob { const float* in; int K, N, tstart, ooff; };
struct WtArgs { WtJob j[10]; };

__global__ __launch_bounds__(256)
void transpose_weights(WtArgs args, __hip_bfloat16* __restrict__ out,
                       const int* __restrict__ ei, int* __restrict__ meta,
                       float* __restrict__ logitsZ) {
  int b = blockIdx.x;
  if (b >= 977) {   // zero logits: 168 blocks x 4096 floats = 688128
    int base = (b - 977) * 4096 + threadIdx.x * 4;
    *(float4*)&logitsZ[base] = (float4){0.f, 0.f, 0.f, 0.f};
    return;
  }
  if (b == 976) {   // build_graph job
    __shared__ int cnt[N_NODES];
    int tid = threadIdx.x;
    if (tid < N_NODES) cnt[tid] = 0;
    __syncthreads();
    if (tid < E_TOT) {
      int s, d;
      if (tid < E_BASE) { s = ei[tid]; d = ei[B_GRAPH * E_BASE + tid]; }
      else              { s = tid - E_BASE; d = s; }
      meta[META_SRC + tid] = s;
      meta[META_DST + tid] = d;
      int pos = atomicAdd(&cnt[d], 1);
      if (pos < MAXIN) meta[META_LIST + d * MAXIN + pos] = (tid << 8) | s;  // packed
    }
    __syncthreads();
    if (tid < N_NODES) meta[META_CNT + tid] = cnt[tid];
    return;
  }
  int ji = 0;
  #pragma unroll
  for (int i = 1; i < 10; i++) if (b >= args.j[i].tstart) ji = i;
  WtJob jb = args.j[ji];
  int t = b - jb.tstart;
  int ntn = jb.N >> 5;
  int tk = t / ntn, tn = t - tk * ntn;
  int k0 = tk * 32, n0 = tn * 32;
  __shared__ float s[32][33];
  int tx = threadIdx.x & 31, ty = threadIdx.x >> 5;
  #pragma unroll
  for (int p = 0; p < 4; p++)
    s[ty + p * 8][tx] = jb.in[(size_t)(k0 + ty + p * 8) * jb.N + n0 + tx];
  __syncthreads();
  __hip_bfloat16* o = out + jb.ooff;
  #pragma unroll
  for (int p = 0; p < 4; p++) {
    int n = ty + p * 8;
    o[(size_t)(n0 + n) * jb.K + k0 + tx] = __float2bfloat16(s[tx][n]);
  }
}

// ---------------------------------------------------------------------------
// R22 gemm_gat: layer GEMM with IN-KERNEL edge logits; xr never hits HBM.
// R22: xlr shrunk to [120][XP] — rows 120-127 were pad outputs NEVER READ
// (logit pass reads rows 0-119; global store loops row<120). Union drops
// 34,816 -> 32,768 B, unlocking a 4th/5th resident block per CU (R11 counters:
// occupancy 37% = 3 blocks/CU with VGPR=64 — LDS-allocation-capped; kernel is
// pure latency, all pipes <40%, so resident blocks ARE the latency currency).
// Epilogue clamps lrow<120 (those acc values were clamped-row garbage anyway).
//
// Block (bm, bn): bn = h*4+cg covers head h, channel-group cg (64 ch).
//   cols 0-63  = xl channels (Wl rows), cols 64-127 = xr channels (Wr rows)
// M-tile = 120 rows = 4 WHOLE graphs so every edge's src/dst rows are
// in-block. atomicAdd partials into zeroed logitsG. bf16 rounding points
// identical to the R0 path (logits read back bf16 values).
// ---------------------------------------------------------------------------
#define XP 132   // padded xlr row stride (shorts)
__global__ __launch_bounds__(256)
void gemm_gat(const __hip_bfloat16* __restrict__ A,      // hnb [NTOT][256]
              const __hip_bfloat16* __restrict__ Wl,     // [H*256][256] bf16 (transposed)
              const __hip_bfloat16* __restrict__ Wr,
              const float* __restrict__ blv, const float* __restrict__ brv,
              const float* __restrict__ att,             // [H][256]
              __hip_bfloat16* __restrict__ xlcat,        // [NTOT][H*256]
              float* __restrict__ logitsG,               // [B][H][E_TOT], pre-zeroed
              const int* __restrict__ meta, int H)
{
  union GatSmem {
    struct { short a[2][4096]; short b[2][4096]; } st;   // 32 KB staging
    short xlr[120 * XP];                                  // 31.7 KB epilogue (R22)
  };
  __shared__ GatSmem sm;
  __shared__ int ssrc[E_TOT], sdst[E_TOT];

  const int tid = threadIdx.x;
  const int lane = tid & 63, wave = tid >> 6;
  const int wx = wave & 1, wy = wave >> 1;
  const int bm = blockIdx.x, bn = blockIdx.y;
  const int mrow = lane & 15, quad = lane >> 4;
  const int hh = bn >> 2, cg = bn & 3;
  const int K = HID;

  if (tid < E_TOT) { ssrc[tid] = meta[META_SRC + tid]; sdst[tid] = meta[META_DST + tid]; }

  const int r0 = tid >> 2, kc0 = (tid & 3) * 8;
  const int Ra = bm * 120 + r0;                              // rows 0..63: real
  const int Rb = bm * 120 + (r0 + 64 > 119 ? 119 : r0 + 64); // clamp pad rows
  const __hip_bfloat16* Ag0 = A + (size_t)Ra * K + kc0;
  const __hip_bfloat16* Ag1 = A + (size_t)Rb * K + kc0;
  const int brow = hh * 256 + cg * 64 + r0;                  // r0 in 0..63
  const __hip_bfloat16* Bg0 = Wl + (size_t)brow * K + kc0;   // cols 0-63  = xl
  const __hip_bfloat16* Bg1 = Wr + (size_t)brow * K + kc0;   // cols 64-127= xr

  f32x4 acc[4][4];
  #pragma unroll
  for (int i = 0; i < 4; i++)
    #pragma unroll
    for (int j = 0; j < 4; j++)
      acc[i][j] = (f32x4){0.f, 0.f, 0.f, 0.f};

  for (int kt = 0; kt < K; kt += 64) {
    __syncthreads();
    #pragma unroll
    for (int s = 0; s < 2; s++) {
      gload_lds16(Ag0 + kt + s * 32, &sm.st.a[s][tid * 8]);
      gload_lds16(Ag1 + kt + s * 32, &sm.st.a[s][2048 + tid * 8]);
      gload_lds16(Bg0 + kt + s * 32, &sm.st.b[s][tid * 8]);
      gload_lds16(Bg1 + kt + s * 32, &sm.st.b[s][2048 + tid * 8]);
    }
    __syncthreads();

    #pragma unroll
    for (int s = 0; s < 2; s++) {
      bf16x8 af[4], bfr[4];
      #pragma unroll
      for (int i = 0; i < 4; i++) {
        af[i]  = *(const bf16x8*)&sm.st.a[s][(wy * 64 + i * 16 + mrow) * 32 + quad * 8];
        bfr[i] = *(const bf16x8*)&sm.st.b[s][(wx * 64 + i * 16 + mrow) * 32 + quad * 8];
      }
      #pragma unroll
      for (int i = 0; i < 4; i++)
        #pragma unroll
        for (int j = 0; j < 4; j++)
          acc[i][j] = __builtin_amdgcn_mfma_f32_16x16x32_bf16(bfr[j], af[i], acc[i][j], 0, 0, 0);
    }
  }

  __syncthreads();   // K-loop LDS reads done; safe to repurpose union as xlr

  // ---- epilogue (transposed fragment): bias + bf16 -> LDS, ds_write_b64.
  // acc[i][j][r] = C[row = wy*64+i*16+mrow][col = wx*64+j*16+quad*4+r]
  // R22: rows >= 120 discarded (pad outputs, never read).
  const float* bb = wx ? brv : blv;
  #pragma unroll
  for (int i = 0; i < 4; i++) {
    int lrow = wy * 64 + i * 16 + mrow;
    if (lrow < 120) {
      #pragma unroll
      for (int j = 0; j < 4; j++) {
        int c0 = j * 16 + quad * 4;               // 0..63 within half
        float4 bc = *(const float4*)&bb[hh * 256 + cg * 64 + c0];
        short t[4];
        t[0] = f2bf_bits(acc[i][j][0] + bc.x);
        t[1] = f2bf_bits(acc[i][j][1] + bc.y);
        t[2] = f2bf_bits(acc[i][j][2] + bc.z);
        t[3] = f2bf_bits(acc[i][j][3] + bc.w);
        *(bf16x4*)&sm.xlr[lrow * XP + wx * 64 + c0] = *(bf16x4*)t;
      }
    }
  }
  __syncthreads();

  // ---- logit partials: 8 lanes/edge x 8 ch; graph-outer, no division.
  const int slot = tid >> 3, esub = tid & 7;   // 32 edge-slots, 8 lanes/edge
  float av[8];
  #pragma unroll
  for (int i = 0; i < 8; i++) av[i] = att[hh * HID + cg * 64 + esub * 8 + i];
  #pragma unroll
  for (int gl = 0; gl < 4; gl++) {
    #pragma unroll
    for (int p = 0; p < 4; p++) {
      int e = p * 32 + slot;
      if (e < E_TOT) {
        int rs = gl * 30 + ssrc[e], rd = gl * 30 + sdst[e];
        bf16x8 xlv = *(const bf16x8*)&sm.xlr[rs * XP + esub * 8];
        bf16x8 xrv = *(const bf16x8*)&sm.xlr[rd * XP + 64 + esub * 8];
        float sum = 0.f;
        #pragma unroll
        for (int i = 0; i < 8; i++) {
          float z = b2f(xlv[i]) + b2f(xrv[i]);
          z = fmaxf(z, 0.2f * z);               // == lrelu(z,0.2), 2 inst
          sum = fmaf(z, av[i], sum);
        }
        sum += __shfl_xor(sum, 1);
        sum += __shfl_xor(sum, 2);
        sum += __shfl_xor(sum, 4);
        if (esub == 0)
          atomicAdd(&logitsG[((size_t)(bm * 4 + gl) * H + hh) * E_TOT + e], sum);
      }
    }
  }

  // ---- cooperative vectorized store of the xl half (120 rows x 64 ch) ----
  // (after the logit pass — fire-and-forget stores, R21)
  {
    const size_t SROW = (size_t)H * HID;
    #pragma unroll
    for (int p = 0; p < 4; p++) {
      int c = tid + p * 256;
      if (c < 960) {
        int row = c >> 3, part = c & 7;
        bf16x8 v = *(const bf16x8*)&sm.xlr[row * XP + part * 8];
        *(bf16x8*)&((short*)xlcat)[((size_t)bm * 120 + row) * SROW
                                   + hh * HID + cg * 64 + part * 8] = v;
      }
    }
  }
}

// ---------------------------------------------------------------------------
// MFMA GEMM with fp32 A staged via in-register bf16 cast (fused cast): proj.
// (EXACT R0 version.)
// ---------------------------------------------------------------------------
template<int ACT, int OUTBF>
__global__ __launch_bounds__(256)
void gemm_mfma_f32a(const float* __restrict__ A, const __hip_bfloat16* __restrict__ Bt,
                    const float* __restrict__ bias, void* __restrict__ Cv,
                    int M, int K, int N)
{
  __shared__ __hip_bfloat16 sA[128 * 32];
  __shared__ __hip_bfloat16 sB[128 * 32];
  const int tid = threadIdx.x;
  const int lane = tid & 63;
  const int wave = tid >> 6;
  const int wx = wave & 1, wy = wave >> 1;
  const int bm = blockIdx.x, bn = blockIdx.y;
  const int mrow = lane & 15, quad = lane >> 4;

  const int r0 = tid >> 2, kc0 = (tid & 3) * 8;
  const float* Ag0 = A + (size_t)(bm * 128 + r0) * K + kc0;
  const float* Ag1 = A + (size_t)(bm * 128 + r0 + 64) * K + kc0;
  const __hip_bfloat16* Bg0 = Bt + (size_t)(bn * 128 + r0) * K + kc0;
  const __hip_bfloat16* Bg1 = Bt + (size_t)(bn * 128 + r0 + 64) * K + kc0;

  f32x4 acc[4][4];
  #pragma unroll
  for (int i = 0; i < 4; i++)
    #pragma unroll
    for (int j = 0; j < 4; j++)
      acc[i][j] = (f32x4){0.f, 0.f, 0.f, 0.f};

  for (int kt = 0; kt < K; kt += 32) {
    float4 a00 = *(const float4*)(Ag0 + kt);
    float4 a01 = *(const float4*)(Ag0 + kt + 4);
    float4 a10 = *(const float4*)(Ag1 + kt);
    float4 a11 = *(const float4*)(Ag1 + kt + 4);
    __syncthreads();
    {
      __hip_bfloat16 t[8];
      t[0] = __float2bfloat16(a00.x); t[1] = __float2bfloat16(a00.y);
      t[2] = __float2bfloat16(a00.z); t[3] = __float2bfloat16(a00.w);
      t[4] = __float2bfloat16(a01.x); t[5] = __float2bfloat16(a01.y);
      t[6] = __float2bfloat16(a01.z); t[7] = __float2bfloat16(a01.w);
      *(bf16x8*)&sA[tid * 8] = *(bf16x8*)t;
      t[0] = __float2bfloat16(a10.x); t[1] = __float2bfloat16(a10.y);
      t[2] = __float2bfloat16(a10.z); t[3] = __float2bfloat16(a10.w);
      t[4] = __float2bfloat16(a11.x); t[5] = __float2bfloat16(a11.y);
      t[6] = __float2bfloat16(a11.z); t[7] = __float2bfloat16(a11.w);
      *(bf16x8*)&sA[2048 + tid * 8] = *(bf16x8*)t;
    }
    gload_lds16(Bg0 + kt, &sB[tid * 8]);
    gload_lds16(Bg1 + kt, &sB[2048 + tid * 8]);
    __syncthreads();

    bf16x8 af[4], bfr[4];
    #pragma unroll
    for (int i = 0; i < 4; i++) {
      af[i]  = *(const bf16x8*)&sA[(wy * 64 + i * 16 + mrow) * 32 + quad * 8];
      bfr[i] = *(const bf16x8*)&sB[(wx * 64 + i * 16 + mrow) * 32 + quad * 8];
    }
    #pragma unroll
    for (int i = 0; i < 4; i++)
      #pragma unroll
      for (int j = 0; j < 4; j++)
        acc[i][j] = __builtin_amdgcn_mfma_f32_16x16x32_bf16(af[i], bfr[j], acc[i][j], 0, 0, 0);
  }

  #pragma unroll
  for (int i = 0; i < 4; i++) {
    #pragma unroll
    for (int r = 0; r < 4; r++) {
      size_t row = (size_t)bm * 128 + wy * 64 + i * 16 + quad * 4 + r;
      #pragma unroll
      for (int j = 0; j < 4; j++) {
        int col = bn * 128 + wx * 64 + j * 16 + mrow;
        float v = acc[i][j][r] + bias[col];
        if (ACT) v = v > 0.f ? v : 0.01f * v;
        if (OUTBF) ((__hip_bfloat16*)Cv)[row * N + col] = __float2bfloat16(v);
        else       ((float*)Cv)[row * N + col] = v;
      }
    }
  }
}

// ---------------------------------------------------------------------------
// R20 gemm_mfma_pair: fused edge-pair gather GEMM, A read from the bf16 h copy
// (hb, written by gat_agg l=2 with identical __float2bfloat16 rounding).
// A staged by DIRECT per-lane global_load_lds.
// A-row r = concat(hb[b,u], hb[b,v]) with b=r/41, (u,v)=pairs[r%41]; K=512.
// C = lrelu(A @ Bt + bias), bf16 out.
// ---------------------------------------------------------------------------
__global__ __launch_bounds__(256)
void gemm_mfma_pair(const __hip_bfloat16* __restrict__ hb, const int* __restrict__ pairs,
                    const __hip_bfloat16* __restrict__ Bt, const float* __restrict__ bias,
                    __hip_bfloat16* __restrict__ C, int N)
{
  const int K = 512;
  __shared__ __hip_bfloat16 sA[128 * 32];
  __shared__ __hip_bfloat16 sB[128 * 32];
  const int tid = threadIdx.x;
  const int lane = tid & 63;
  const int wave = tid >> 6;
  const int wx = wave & 1, wy = wave >> 1;
  const int bm = blockIdx.x, bn = blockIdx.y;
  const int mrow = lane & 15, quad = lane >> 4;

  const __hip_bfloat16* pu[2]; const __hip_bfloat16* pv[2]; int sub[2];
  #pragma unroll
  for (int cI = 0; cI < 2; cI++) {
    int c = tid + cI * 256;
    int rc = c >> 2; sub[cI] = (c & 3) * 8;        // 8-ch (16B) sub-chunk
    int R = bm * 128 + rc;
    int b = R / N_EH, p = R - b * N_EH;
    int u = pairs[p * 2], v = pairs[p * 2 + 1];
    pu[cI] = hb + ((size_t)b * N_NODES + u) * HID;
    pv[cI] = hb + ((size_t)b * N_NODES + v) * HID;
  }

  const int r0 = tid >> 2, kc0 = (tid & 3) * 8;
  const __hip_bfloat16* Bg0 = Bt + (size_t)(bn * 128 + r0) * K + kc0;
  const __hip_bfloat16* Bg1 = Bt + (size_t)(bn * 128 + r0 + 64) * K + kc0;

  f32x4 acc[4][4];
  #pragma unroll
  for (int i = 0; i < 4; i++)
    #pragma unroll
    for (int j = 0; j < 4; j++)
      acc[i][j] = (f32x4){0.f, 0.f, 0.f, 0.f};

  for (int kt = 0; kt < K; kt += 32) {
    __syncthreads();
    #pragma unroll
    for (int cI = 0; cI < 2; cI++) {
      const __hip_bfloat16* src = (kt < 256 ? pu[cI] + kt : pv[cI] + kt - 256) + sub[cI];
      gload_lds16(src, &sA[(size_t)(tid + cI * 256) * 8]);
    }
    gload_lds16(Bg0 + kt, &sB[tid * 8]);
    gload_lds16(Bg1 + kt, &sB[2048 + tid * 8]);
    __syncthreads();

    bf16x8 af[4], bfr[4];
    #pragma unroll
    for (int i = 0; i < 4; i++) {
      af[i]  = *(const bf16x8*)&sA[(wy * 64 + i * 16 + mrow) * 32 + quad * 8];
      bfr[i] = *(const bf16x8*)&sB[(wx * 64 + i * 16 + mrow) * 32 + quad * 8];
    }
    #pragma unroll
    for (int i = 0; i < 4; i++)
      #pragma unroll
      for (int j = 0; j < 4; j++)
        acc[i][j] = __builtin_amdgcn_mfma_f32_16x16x32_bf16(af[i], bfr[j], acc[i][j], 0, 0, 0);
  }

  #pragma unroll
  for (int i = 0; i < 4; i++) {
    #pragma unroll
    for (int r = 0; r < 4; r++) {
      size_t row = (size_t)bm * 128 + wy * 64 + i * 16 + quad * 4 + r;
      #pragma unroll
      for (int j = 0; j < 4; j++) {
        int col = bn * 128 + wx * 64 + j * 16 + mrow;
        float v = acc[i][j][r] + bias[col];
        v = v > 0.f ? v : 0.01f * v;
        C[row * N + col] = __float2bfloat16(v);
      }
    }
  }
}

// ---------------------------------------------------------------------------
// Fused MLP tail (R11 — proven win; EXACT R0 version).
// ---------------------------------------------------------------------------
#define O2P 136
__global__ __launch_bounds__(256)
void mlp_tail(const __hip_bfloat16* __restrict__ o1, const __hip_bfloat16* __restrict__ W1t,
              const float* __restrict__ b1, const __hip_bfloat16* __restrict__ W2t,
              const float* __restrict__ b2, const float* __restrict__ w3,
              const float* __restrict__ b3, float* __restrict__ out)
{
  __shared__ __hip_bfloat16 sA[128 * 32];
  __shared__ __hip_bfloat16 sB[128 * 32];
  __shared__ __hip_bfloat16 sO2[128 * O2P];
  __shared__ float spart[2][128];
  const int tid = threadIdx.x;
  const int lane = tid & 63;
  const int wave = tid >> 6;
  const int wx = wave & 1, wy = wave >> 1;
  const int bm = blockIdx.x;
  const int mrow = lane & 15, quad = lane >> 4;
  const int r0 = tid >> 2, kc0 = (tid & 3) * 8;

  const __hip_bfloat16* Ag0 = o1 + (size_t)(bm * 128 + r0) * 256 + kc0;
  const __hip_bfloat16* Ag1 = o1 + (size_t)(bm * 128 + r0 + 64) * 256 + kc0;
  const __hip_bfloat16* Bg0 = W1t + (size_t)r0 * 256 + kc0;
  const __hip_bfloat16* Bg1 = W1t + (size_t)(r0 + 64) * 256 + kc0;

  f32x4 acc[4][4];
  #pragma unroll
  for (int i = 0; i < 4; i++)
    #pragma unroll
    for (int j = 0; j < 4; j++)
      acc[i][j] = (f32x4){0.f, 0.f, 0.f, 0.f};

  for (int kt = 0; kt < 256; kt += 32) {
    __syncthreads();
    gload_lds16(Ag0 + kt, &sA[tid * 8]);
    gload_lds16(Ag1 + kt, &sA[2048 + tid * 8]);
    gload_lds16(Bg0 + kt, &sB[tid * 8]);
    gload_lds16(Bg1 + kt, &sB[2048 + tid * 8]);
    __syncthreads();

    bf16x8 af[4], bfr[4];
    #pragma unroll
    for (int i = 0; i < 4; i++) {
      af[i]  = *(const bf16x8*)&sA[(wy * 64 + i * 16 + mrow) * 32 + quad * 8];
      bfr[i] = *(const bf16x8*)&sB[(wx * 64 + i * 16 + mrow) * 32 + quad * 8];
    }
    #pragma unroll
    for (int i = 0; i < 4; i++)
      #pragma unroll
      for (int j = 0; j < 4; j++)
        acc[i][j] = __builtin_amdgcn_mfma_f32_16x16x32_bf16(af[i], bfr[j], acc[i][j], 0, 0, 0);
  }

  __syncthreads();
  #pragma unroll
  for (int i = 0; i < 4; i++) {
    #pragma unroll
    for (int r = 0; r < 4; r++) {
      int row = wy * 64 + i * 16 + quad * 4 + r;
      #pragma unroll
      for (int j = 0; j < 4; j++) {
        int col = wx * 64 + j * 16 + mrow;
        float v = acc[i][j][r] + b1[col];
        v = v > 0.f ? v : 0.01f * v;
        sO2[row * O2P + col] = __float2bfloat16(v);
      }
    }
  }

  f32x4 acc2[4][4];
  #pragma unroll
  for (int i = 0; i < 4; i++)
    #pragma unroll
    for (int j = 0; j < 4; j++)
      acc2[i][j] = (f32x4){0.f, 0.f, 0.f, 0.f};

  for (int kt = 0; kt < 128; kt += 32) {
    __syncthreads();
    gload_lds16(W2t + (size_t)r0 * 128 + kt + kc0, &sB[tid * 8]);
    gload_lds16(W2t + (size_t)(r0 + 64) * 128 + kt + kc0, &sB[2048 + tid * 8]);
    __syncthreads();

    bf16x8 af[4], bfr[4];
    #pragma unroll
    for (int i = 0; i < 4; i++) {
      af[i]  = *(const bf16x8*)&sO2[(wy * 64 + i * 16 + mrow) * O2P + kt + quad * 8];
      bfr[i] = *(const bf16x8*)&sB[(wx * 64 + i * 16 + mrow) * 32 + quad * 8];
    }
    #pragma unroll
    for (int i = 0; i < 4; i++)
      #pragma unroll
      for (int j = 0; j < 4; j++)
        acc2[i][j] = __builtin_amdgcn_mfma_f32_16x16x32_bf16(af[i], bfr[j], acc2[i][j], 0, 0, 0);
  }

  float w3v[4], b2v[4];
  #pragma unroll
  for (int j = 0; j < 4; j++) {
    int col = wx * 64 + j * 16 + mrow;
    w3v[j] = w3[col];
    b2v[j] = b2[col];
  }
  #pragma unroll
  for (int i = 0; i < 4; i++) {
    #pragma unroll
    for (int r = 0; r < 4; r++) {
      float s = 0.f;
      #pragma unroll
      for (int j = 0; j < 4; j++) {
        float v = acc2[i][j][r] + b2v[j];
        v = v > 0.f ? v : 0.01f * v;
        s += v * w3v[j];
      }
      #pragma unroll
      for (int off = 8; off; off >>= 1) s += __shfl_xor(s, off);
      if (mrow == 0) {
        int row = wy * 64 + i * 16 + quad * 4 + r;
        spart[wx][row] = s;
      }
    }
  }
  __syncthreads();
  if (tid < 128)
    out[(size_t)bm * 128 + tid] = spart[0][tid] + spart[1][tid] + b3[0];
}

// ---------------------------------------------------------------------------
// LayerNorm over HID=256; one wave per row; R21: float4 (16B) loads/stores —
// lane covers channels [lane*4, lane*4+4).
// ---------------------------------------------------------------------------
__global__ __launch_bounds__(256)
void layernorm(const float* __restrict__ h, const float* __restrict__ g,
               const float* __restrict__ b, __hip_bfloat16* __restrict__ hn)
{
  const int wv = threadIdx.x >> 6, lane = threadIdx.x & 63;
  const size_t row = (size_t)blockIdx.x * 4 + wv;
  const float* hr = h + row * HID;
  float4 v = *(const float4*)&hr[lane * 4];
  float sum = v.x + v.y + v.z + v.w;
  #pragma unroll
  for (int off = 32; off; off >>= 1) sum += __shfl_xor(sum, off);
  float mu = sum * (1.f / 256.f);
  float d0 = v.x - mu, d1 = v.y - mu, d2 = v.z - mu, d3 = v.w - mu;
  float vs = d0 * d0 + d1 * d1 + d2 * d2 + d3 * d3;
  #pragma unroll
  for (int off = 32; off; off >>= 1) vs += __shfl_xor(vs, off);
  float rs = rsqrtf(vs * (1.f / 256.f) + 1e-5f);
  float4 gv = *(const float4*)&g[lane * 4];
  float4 bv = *(const float4*)&b[lane * 4];
  short t[4];
  t[0] = f2bf_bits(d0 * rs * gv.x + bv.x);
  t[1] = f2bf_bits(d1 * rs * gv.y + bv.y);
  t[2] = f2bf_bits(d2 * rs * gv.z + bv.z);
  t[3] = f2bf_bits(d3 * rs * gv.w + bv.w);
  *(bf16x4*)&hn[row * HID + lane * 4] = *(bf16x4*)t;
}

// ---------------------------------------------------------------------------
// R21 gat_agg: aggregation + h update with CONCURRENT all-head softmax (3
// barriers; logits padded to [hh*128+e]; per-(head,node) max as
// tid=(hh<<5)|node). Agg inner loop uses the PACKED slist ((e<<8)|src).
// For DO_LN==0 (last layer) writes a bf16 copy of the final h to hn (=hnb)
// for gemm_mfma_pair's gather. xcat is xl-only: row stride S = H*HID.
// One block per graph; thread = (channel-quad c4, node-group ng).
// ---------------------------------------------------------------------------
template<int DO_LN>
__global__ __launch_bounds__(256, 4)
void gat_agg(const __hip_bfloat16* __restrict__ xcat, const float* __restrict__ logitsG,
             const float* __restrict__ bias, float* __restrict__ h,
             const float* __restrict__ lnG, const float* __restrict__ lnB,
             __hip_bfloat16* __restrict__ hn, const int* __restrict__ meta, int H)
{
  __shared__ __hip_bfloat16 sxl[2][N_NODES * HID];   // 2 x 15 KB, head double-buffer
  __shared__ float slogA[3 * 128], salphaA[3 * 128]; // [hh*128 + e]
  __shared__ float smaxA[3 * 32], sdenA[3 * 32];     // [hh*32 + node]
  __shared__ int sdst[E_TOT], scnt[N_NODES], slist[N_NODES * MAXIN];

  const int tid = threadIdx.x;
  const int g = blockIdx.x;
  const size_t nodebase = (size_t)g * N_NODES;
  const int S = H * HID;                    // xl-only stride
  const int c4 = tid & 63;
  const int ng = tid >> 6;

  if (tid < E_TOT) sdst[tid] = meta[META_DST + tid];
  if (tid < N_NODES) scnt[tid] = meta[META_CNT + tid];
  for (int i = tid; i < N_NODES * MAXIN; i += 256) slist[i] = meta[META_LIST + i];

  float4 hres[8];
  #pragma unroll
  for (int ki = 0; ki < 8; ki++) {
    int k = ng + ki * 4;
    if (k < N_NODES) hres[ki] = *(const float4*)&h[(nodebase + k) * HID + c4 * 4];
  }

  // issue stage of head 0's xl (async; overlaps with the softmax below)
  {
    int i = tid;
    #pragma unroll
    for (int p = 0; p < 4; p++, i += 256) {
      if (i < N_NODES * HID / 8) {
        int node = i >> 5, c = (i & 31) * 8;
        gload_lds16(&xcat[(nodebase + node) * S + 0 * HID + c], &sxl[0][(size_t)i * 8]);
      }
    }
  }

  // ---- concurrent all-head softmax (3 barriers total) ----
  for (int i = tid; i < H * 128; i += 256) {
    int hh = i >> 7, e = i & 127;
    if (e < E_TOT) slogA[i] = logitsG[((size_t)g * H + hh) * E_TOT + e];
  }
  if (tid < H * 32) sdenA[tid] = 0.f;
  __syncthreads();
  {
    int hh = tid >> 5, node = tid & 31;
    if (hh < H && node < N_NODES) {
      int cnt = scnt[node];
      const int* lst = &slist[node * MAXIN];
      float m = -1e30f;
      for (int i = 0; i < cnt; i++) m = fmaxf(m, slogA[(hh << 7) + (lst[i] >> 8)]);
      smaxA[tid] = m;
    }
  }
  __syncthreads();
  for (int i = tid; i < H * 128; i += 256) {
    int hh = i >> 7, e = i & 127;
    if (e < E_TOT) {
      float ex = expf(slogA[i] - smaxA[(hh << 5) + sdst[e]]);
      slogA[i] = ex;
      atomicAdd(&sdenA[(hh << 5) + sdst[e]], ex);
    }
  }
  __syncthreads();
  for (int i = tid; i < H * 128; i += 256) {
    int hh = i >> 7, e = i & 127;
    if (e < E_TOT) salphaA[i] = slogA[i] / sdenA[(hh << 5) + sdst[e]];
  }
  // first agg loop-head barrier covers salphaA visibility + xl[0] drain

  float acc[8][4];
  #pragma unroll
  for (int ki = 0; ki < 8; ki++)
    #pragma unroll
    for (int j = 0; j < 4; j++) acc[ki][j] = 0.f;

  for (int hh = 0; hh < H; hh++) {
    const int buf = hh & 1;
    __syncthreads();   // staged loads drained; salphaA ready (first iter)
    if (hh + 1 < H) {
      const int nb = buf ^ 1;
      int i = tid;
      #pragma unroll
      for (int p = 0; p < 4; p++, i += 256) {
        if (i < N_NODES * HID / 8) {
          int node = i >> 5, c = (i & 31) * 8;
          gload_lds16(&xcat[(nodebase + node) * S + (hh + 1) * HID + c], &sxl[nb][(size_t)i * 8]);
        }
      }
    }
    #pragma unroll
    for (int ki = 0; ki < 8; ki++) {
      int k = ng + ki * 4;
      if (k < N_NODES) {
        int cnt = scnt[k];
        const int* lst = &slist[k * MAXIN];
        for (int i = 0; i < cnt; i++) {
          int pk = lst[i];                      // packed (e<<8)|src, wave-uniform
          float al = salphaA[(hh << 7) + (pk >> 8)];
          bf16x4 v = *(const bf16x4*)&sxl[buf][(pk & 255) * HID + c4 * 4];
          acc[ki][0] += al * b2f(v[0]);
          acc[ki][1] += al * b2f(v[1]);
          acc[ki][2] += al * b2f(v[2]);
          acc[ki][3] += al * b2f(v[3]);
        }
      }
    }
  }

  const float invH = 1.f / (float)H;
  const float4 bs = *(const float4*)&bias[c4 * 4];
  float4 gv, bv;
  if (DO_LN) {
    gv = *(const float4*)&lnG[c4 * 4];
    bv = *(const float4*)&lnB[c4 * 4];
  }
  #pragma unroll
  for (int ki = 0; ki < 8; ki++) {
    int k = ng + ki * 4;
    if (k < N_NODES) {
      float o0 = acc[ki][0] * invH + bs.x; o0 = o0 > 0.f ? o0 : 0.01f * o0; o0 += hres[ki].x;
      float o1 = acc[ki][1] * invH + bs.y; o1 = o1 > 0.f ? o1 : 0.01f * o1; o1 += hres[ki].y;
      float o2 = acc[ki][2] * invH + bs.z; o2 = o2 > 0.f ? o2 : 0.01f * o2; o2 += hres[ki].z;
      float o3 = acc[ki][3] * invH + bs.w; o3 = o3 > 0.f ? o3 : 0.01f * o3; o3 += hres[ki].w;
      float4 o4 = {o0, o1, o2, o3};
      *(float4*)&h[(nodebase + k) * HID + c4 * 4] = o4;
      if (DO_LN) {
        float sum = o0 + o1 + o2 + o3;
        #pragma unroll
        for (int off = 32; off; off >>= 1) sum += __shfl_xor(sum, off);
        float mu = sum * (1.f / 256.f);
        float d0 = o0 - mu, d1 = o1 - mu, d2 = o2 - mu, d3 = o3 - mu;
        float vs = d0 * d0 + d1 * d1 + d2 * d2 + d3 * d3;
        #pragma unroll
        for (int off = 32; off; off >>= 1) vs += __shfl_xor(vs, off);
        float rs = rsqrtf(vs * (1.f / 256.f) + 1e-5f);
        __hip_bfloat16 t[4];
        t[0] = __float2bfloat16(d0 * rs * gv.x + bv.x);
        t[1] = __float2bfloat16(d1 * rs * gv.y + bv.y);
        t[2] = __float2bfloat16(d2 * rs * gv.z + bv.z);
        t[3] = __float2bfloat16(d3 * rs * gv.w + bv.w);
        *(bf16x4*)&hn[(nodebase + k) * HID + c4 * 4] = *(bf16x4*)t;
      } else {
        // bf16 copy of final h for the pair-GEMM gather (R20)
        short t[4];
        t[0] = f2bf_bits(o0); t[1] = f2bf_bits(o1);
        t[2] = f2bf_bits(o2); t[3] = f2bf_bits(o3);
        *(bf16x4*)&hn[(nodebase + k) * HID + c4 * 4] = *(bf16x4*)t;
      }
    }
  }
}

// ---------------------------------------------------------------------------
extern "C" void kernel_launch(void* const* d_in, const int* in_sizes, int n_in,
                              void* d_out, int out_size, void* d_ws, size_t ws_size,
                              hipStream_t stream) {
  const float* x     = (const float*)d_in[0];
  const int*   ei    = (const int*)d_in[1];
  const int*   pairs = (const int*)d_in[2];
  const float* bp    = (const float*)d_in[4];
  const float *lng[3], *lnb[3], *bl[3], *br[3], *att[3], *bias[3];
  const float *WlF[3], *WrF[3];
  for (int l = 0; l < 3; l++) {
    int base = 5 + l * 8;
    lng[l]  = (const float*)d_in[base + 0];
    lnb[l]  = (const float*)d_in[base + 1];
    WlF[l]  = (const float*)d_in[base + 2];
    bl[l]   = (const float*)d_in[base + 3];
    WrF[l]  = (const float*)d_in[base + 4];
    br[l]   = (const float*)d_in[base + 5];
    att[l]  = (const float*)d_in[base + 6];
    bias[l] = (const float*)d_in[base + 7];
  }
  const float* WmF[4] = {(const float*)d_in[29], (const float*)d_in[31],
                         (const float*)d_in[33], (const float*)d_in[35]};
  const float* bm[4] = {(const float*)d_in[30], (const float*)d_in[32],
                        (const float*)d_in[34], (const float*)d_in[36]};

  // workspace layout (float offsets)
  float* ws  = (float*)d_ws;
  float* h   = ws;                                           // [0, 7864320)
  __hip_bfloat16* hnb = (__hip_bfloat16*)(ws + 7864320);     // 3,932,160 bf
  __hip_bfloat16* xlcat = (__hip_bfloat16*)(ws + 11796480);  // xl-only: <= 23,592,960 bf
  float* logits0 = ws + 30000000;                            // 344,064 f (l=0)
  float* logits1 = logits0 + 344064;                         // 229,376 f (l=1)
  float* logits2 = logits1 + 229376;                         // 114,688 f (l=2)
  __hip_bfloat16* wbuf = (__hip_bfloat16*)(ws + 35733504);   // 999,424 bf
  int*   meta = (int*)(ws + 36233216);
  __hip_bfloat16* o1b = (__hip_bfloat16*)xlcat;              // pair out (xlcat dead then)
  float* out = (float*)d_out;

  // bf16 transposed weight offsets (layouts unchanged from R0)
  const int oWp = 0, oWl0 = 32768, oWr0 = 229376, oWl1 = 425984, oWr1 = 557056;
  const int oWl2 = 688128, oWr2 = 753664, oWm0 = 819200, oWm1 = 950272, oWm2 = 983040;

  WtArgs wa;
  wa.j[0] = {(const float*)d_in[3], 128, 256,   0, oWp };
  wa.j[1] = {WlF[0],              256, 768,  32, oWl0};
  wa.j[2] = {WrF[0],              256, 768, 224, oWr0};
  wa.j[3] = {WlF[1],              256, 512, 416, oWl1};
  wa.j[4] = {WrF[1],              256, 512, 544, oWr1};
  wa.j[5] = {WlF[2],              256, 256, 672, oWl2};
  wa.j[6] = {WrF[2],              256, 256, 736, oWr2};
  wa.j[7] = {WmF[0],              512, 256, 800, oWm0};
  wa.j[8] = {WmF[1],              256, 128, 928, oWm1};
  wa.j[9] = {WmF[2],              128, 128, 960, oWm2};
  // blocks 0-975: transpose jobs; 976: build_graph; 977-1144: zero logits
  transpose_weights<<<1145, 256, 0, stream>>>(wa, wbuf, ei, meta, logits0);

  // h = x @ Wp + bp   (fp32 A staged with fused bf16 cast; fp32 out)
  gemm_mfma_f32a<0, 0><<<dim3(NTOT / 128, 2), 256, 0, stream>>>(x, wbuf + oWp, bp, h,
                                                                NTOT, 128, 256);

  layernorm<<<NTOT / 4, 256, 0, stream>>>(h, lng[0], lnb[0], hnb);

  const int Hs[3] = {3, 2, 1};
  const int oWl[3] = {oWl0, oWl1, oWl2};
  const int oWr[3] = {oWr0, oWr1, oWr2};
  float* logitsL[3] = {logits0, logits1, logits2};
  for (int l = 0; l < 3; l++) {
    int H = Hs[l];
    gemm_gat<<<dim3(NTOT / 120, H * 4), 256, 0, stream>>>(
        hnb, wbuf + oWl[l], wbuf + oWr[l], bl[l], br[l], att[l],
        xlcat, logitsL[l], meta, H);
    if (l < 2)
      gat_agg<1><<<B_GRAPH, 256, 0, stream>>>(xlcat, logitsL[l], bias[l], h,
                                              lng[l + 1], lnb[l + 1], hnb, meta, H);
    else
      gat_agg<0><<<B_GRAPH, 256, 0, stream>>>(xlcat, logitsL[l], bias[l], h,
                                              nullptr, nullptr, hnb, meta, H);
  }

  // pair-GEMM reads the bf16 h copy (hnb) written by gat_agg l=2
  gemm_mfma_pair<<<dim3(M_MLP / 128, 2), 256, 0, stream>>>(hnb, pairs, wbuf + oWm0, bm[0], o1b, 256);
  mlp_tail<<<M_MLP / 128, 256, 0, stream>>>(o1b, wbuf + oWm1, bm[1], wbuf + oWm2, bm[2],
                                            WmF[3], bm[3], out);
}